// Round 11
// baseline (598.181 us; speedup 1.0000x reference)
//
#include <hip/hip_runtime.h>
#include <hip/hip_cooperative_groups.h>
#include <math.h>

namespace cg = cooperative_groups;

// ---------------------------------------------------------------------------
// GCN forward, numerically matched to the numpy float32 reference:
//  - GEMMs: per-element sequential-k fp32 FMA chain (== BLAS sgemm microkernel)
//  - segment_sum: per-feature fp32 adds in ascending-edge order (== np.add.at)
//  - head final dot: f64 (no downstream amplification)
// NUMERICS ARE LOCKED (absmax 1e-13 since round 3): only scheduling/memory
// layout may change between rounds, never the fp32 op order.
//
// CSR build (round 11): ONE cooperative kernel fusing
//   P1 per-block hist(dst>>8) -> P2 per-digit row scan (LDS) -> P3 digit-base
//   scan -> P4 stable ballot-rank scatter -> P5 per-digit LDS counting sort
//   by low byte (emits csr_src + offs). 4x grid.sync(); order (dst, e) ==
//   np.add.at. Replaces 6 small dispatches (launch-gap bound).
// Aggregation = round-6 measured variant (107us, 344MB fetch ~= compulsory
// floor @ ~3.5TB/s L2-fill). DO NOT TOUCH (round-7 lesson).
// GEMM v3 = round-10 (near its memory/VALU floor).
// ---------------------------------------------------------------------------

typedef unsigned long long u64;

#define RB_SIZE    4096
#define RB_ROUNDS  16     // RB_SIZE / 256
#define BUCKET_CAP 9216   // mean 8192, sigma ~90 -> +11 sigma

// Fused sort: grid = NBLK blocks x 256 threads; all blocks hit every sync.
// LDS layout (55 KB): srcs int[9216] | lob u8[9216] | A int[256] | B int[256]
//                     | C int[1024] (16B-aligned) | D int[1024]
__global__ __launch_bounds__(256) void sort_coop(const int* __restrict__ dstArr,
                                                 const int* __restrict__ srcArr,
                                                 u64* __restrict__ rec,
                                                 int* __restrict__ bh,
                                                 int* __restrict__ dtot,
                                                 int* __restrict__ csr_src,
                                                 int* __restrict__ offs,
                                                 int E, int N, int NBLK, int NDIG) {
    __shared__ int smem[14080];
    int* srcs = smem;
    unsigned char* lob = (unsigned char*)(smem + 9216);
    int* A = smem + 11520;
    int* B = smem + 11776;
    int* C = smem + 12032;   // byte 48128: 16B-aligned
    int* D = smem + 13056;

    cg::grid_group grid = cg::this_grid();
    int tid = threadIdx.x;
    int b = blockIdx.x;
    int wid = tid >> 6, lane = tid & 63;

    // --- P1: per-block histogram of dst>>8, digit-major bh[d*NBLK+b] ---
    if (b < NBLK) {
        A[tid] = 0;
        __syncthreads();
        int base = b * RB_SIZE;
        for (int t = tid; t < RB_SIZE; t += 256) {
            int i = base + t;
            if (i < E) atomicAdd(&A[dstArr[i] >> 8], 1);
        }
        __syncthreads();
        if (tid < NDIG) bh[tid * NBLK + b] = A[tid];
    }
    grid.sync();

    // --- P2: per-digit exclusive scan of its NBLK row (in place) + total ---
    if (b < NDIG) {
        int running = 0;
        for (int base = 0; base < NBLK; base += 512) {
            int i0 = base + tid, i1 = base + tid + 256;
            int v0 = (i0 < NBLK) ? bh[b * NBLK + i0] : 0;
            int v1 = (i1 < NBLK) ? bh[b * NBLK + i1] : 0;
            srcs[tid] = v0; srcs[tid + 256] = v1;
            __syncthreads();
            for (int s = 1; s < 512; s <<= 1) {
                int a0 = (tid >= s) ? srcs[tid - s] : 0;
                int a1 = (tid + 256 >= s) ? srcs[tid + 256 - s] : 0;
                __syncthreads();
                srcs[tid] += a0; srcs[tid + 256] += a1;
                __syncthreads();
            }
            if (i0 < NBLK) bh[b * NBLK + i0] = running + srcs[tid] - v0;
            if (i1 < NBLK) bh[b * NBLK + i1] = running + srcs[tid + 256] - v1;
            running += srcs[511];
            __syncthreads();
        }
        if (tid == 0) dtot[b] = running;
    }
    grid.sync();

    // --- P3: exclusive scan of NDIG digit totals (block 0) -> dtot = dbase ---
    if (b == 0) {
        int v = (tid < NDIG) ? dtot[tid] : 0;
        srcs[tid] = v;
        __syncthreads();
        for (int s = 1; s < 256; s <<= 1) {
            int u = (tid >= s) ? srcs[tid - s] : 0;
            __syncthreads();
            srcs[tid] += u;
            __syncthreads();
        }
        if (tid < NDIG) dtot[tid] = srcs[tid] - v;
    }
    grid.sync();

    // --- P4: stable ballot-rank scatter by dst>>8 into rec ---
    if (b < NBLK) {
        B[tid] = 0;   // cursor
        A[tid] = (tid < NDIG) ? dtot[tid] + bh[tid * NBLK + b] : 0;  // gbase
        int base = b * RB_SIZE;
        __syncthreads();
        for (int r = 0; r < RB_ROUNDS; ++r) {
            int i = base + r * 256 + tid;
            bool valid = (i < E);
            int d = 0;
            u64 rc = 0;
            if (valid) {
                int dv = dstArr[i];
                rc = ((u64)(unsigned)srcArr[i] << 32) | (unsigned)dv;
                d = dv >> 8;
            }
            ((int4*)C)[tid] = make_int4(0, 0, 0, 0);
            u64 mask = ~0ull;
#pragma unroll
            for (int bb2 = 0; bb2 < 8; ++bb2) {
                int bit = (d >> bb2) & 1;
                u64 bal = __ballot(bit);
                mask &= bit ? bal : ~bal;
            }
            mask &= __ballot(valid ? 1 : 0);
            int rank = __popcll(mask & (((u64)1 << lane) - 1));
            int wtot = __popcll(mask);
            __syncthreads();
            if (valid && rank == 0) C[d * 4 + wid] = wtot;
            __syncthreads();
            {
                int run = B[tid];
#pragma unroll
                for (int w = 0; w < 4; ++w) {
                    D[tid * 4 + w] = run;
                    run += C[tid * 4 + w];
                }
                B[tid] = run;
            }
            __syncthreads();
            if (valid) rec[A[d] + D[d * 4 + wid] + rank] = rc;
            __syncthreads();
        }
    }
    grid.sync();

    // --- P5: per-digit LDS stable counting sort by low byte -> csr_src+offs ---
    if (b < NDIG) {
        int gbeg = dtot[b];
        int gend = (b + 1 < NDIG) ? dtot[b + 1] : E;
        int cnt = gend - gbeg;
        if (cnt > BUCKET_CAP) cnt = BUCKET_CAP;   // statistically impossible
        A[tid] = 0;   // binb
        __syncthreads();
        for (int i = tid; i < cnt; i += 256) {
            u64 r = rec[gbeg + i];
            srcs[i] = (int)(r >> 32);
            int lo = (int)(r & 255);
            lob[i] = (unsigned char)lo;
            atomicAdd(&A[lo], 1);
        }
        __syncthreads();
        int c = A[tid];
        B[tid] = c;
        __syncthreads();
        for (int s = 1; s < 256; s <<= 1) {
            int v = (tid >= s) ? B[tid - s] : 0;
            __syncthreads();
            B[tid] += v;
            __syncthreads();
        }
        int excl = B[tid] - c;
        __syncthreads();
        B[tid] = excl;    // cursor
        int v = b * 256 + tid;
        if (v < N) offs[v] = gbeg + excl;
        if (b == NDIG - 1 && tid == 0) offs[N] = E;
        __syncthreads();
        int nrounds = (cnt + 255) >> 8;
        for (int r = 0; r < nrounds; ++r) {
            int i = r * 256 + tid;
            bool valid = (i < cnt);
            int d = valid ? (int)lob[i] : 0;
            ((int4*)C)[tid] = make_int4(0, 0, 0, 0);
            u64 mask = ~0ull;
#pragma unroll
            for (int bb2 = 0; bb2 < 8; ++bb2) {
                int bit = (d >> bb2) & 1;
                u64 bal = __ballot(bit);
                mask &= bit ? bal : ~bal;
            }
            mask &= __ballot(valid ? 1 : 0);
            int rank = __popcll(mask & (((u64)1 << lane) - 1));
            int wtot = __popcll(mask);
            __syncthreads();
            if (valid && rank == 0) C[d * 4 + wid] = wtot;
            __syncthreads();
            {
                int run = B[tid];
#pragma unroll
                for (int w = 0; w < 4; ++w) {
                    D[tid * 4 + w] = run;
                    run += C[tid * 4 + w];
                }
                B[tid] = run;
            }
            __syncthreads();
            if (valid) csr_src[gbeg + D[d * 4 + wid] + rank] = srcs[i];
            __syncthreads();
        }
    }
}

// out[M,128] = relu((A (+A2)) @ W[128,128] + bias), fp32 sequential-k FMA
// chain per element (== sgemm). 128x128 block, 8x8 per-thread; As XOR-swizzled.
// K order kh->k4->kk strictly ascending == same chain since round 3.
template <bool FUSE>
__global__ __launch_bounds__(256) void gemm128(const float* __restrict__ A,
                                               const float* __restrict__ A2,
                                               const float* __restrict__ W,
                                               const float* __restrict__ bias,
                                               float* __restrict__ out, int M) {
    __shared__ float As[128 * 64];   // one K-half of A rows, swizzled: 32 KB
    __shared__ float Ws[64 * 128];   // one K-half of W: 32 KB
    int tid = threadIdx.x;
    int tx = tid & 15;
    int ty = tid >> 4;
    int row0 = blockIdx.x * 128;

    float acc[8][8];
#pragma unroll
    for (int r = 0; r < 8; ++r)
#pragma unroll
        for (int c = 0; c < 8; ++c) acc[r][c] = 0.f;

    const float4* A4 = (const float4*)A;
    const float4* A24 = (const float4*)A2;
    const float4* W4 = (const float4*)W;
    float4* As4 = (float4*)As;
    float4* Ws4 = (float4*)Ws;
    int swz = ty & 7;

    for (int kh = 0; kh < 2; ++kh) {
        __syncthreads();
#pragma unroll
        for (int j = 0; j < 8; ++j) {
            int idx = tid + 256 * j;
            int r = idx >> 4, kf = idx & 15;
            int gr = row0 + r;
            float4 v = make_float4(0.f, 0.f, 0.f, 0.f);
            if (gr < M) {
                v = A4[gr * 32 + kh * 16 + kf];
                if (FUSE) {
                    float4 u = A24[gr * 32 + kh * 16 + kf];
                    v.x += u.x; v.y += u.y; v.z += u.z; v.w += u.w;  // agg+h
                }
            }
            As4[r * 16 + (kf ^ ((r >> 3) & 7))] = v;
            int k = idx >> 5, cf = idx & 31;
            Ws4[k * 32 + cf] = W4[(kh * 64 + k) * 32 + cf];
        }
        __syncthreads();

#pragma unroll 2
        for (int k4 = 0; k4 < 16; ++k4) {
            float4 a[8];
#pragma unroll
            for (int r = 0; r < 8; ++r)
                a[r] = As4[(ty * 8 + r) * 16 + (k4 ^ swz)];
#pragma unroll
            for (int kk = 0; kk < 4; ++kk) {
                float4 b0 = Ws4[(k4 * 4 + kk) * 32 + tx];
                float4 b1 = Ws4[(k4 * 4 + kk) * 32 + 16 + tx];
#pragma unroll
                for (int r = 0; r < 8; ++r) {
                    float av = (kk == 0) ? a[r].x : (kk == 1) ? a[r].y
                             : (kk == 2) ? a[r].z : a[r].w;
                    acc[r][0] = fmaf(av, b0.x, acc[r][0]);
                    acc[r][1] = fmaf(av, b0.y, acc[r][1]);
                    acc[r][2] = fmaf(av, b0.z, acc[r][2]);
                    acc[r][3] = fmaf(av, b0.w, acc[r][3]);
                    acc[r][4] = fmaf(av, b1.x, acc[r][4]);
                    acc[r][5] = fmaf(av, b1.y, acc[r][5]);
                    acc[r][6] = fmaf(av, b1.z, acc[r][6]);
                    acc[r][7] = fmaf(av, b1.w, acc[r][7]);
                }
            }
        }
    }

    float4 bv0 = ((const float4*)bias)[tx];
    float4 bv1 = ((const float4*)bias)[16 + tx];
    float4* out4 = (float4*)out;
#pragma unroll
    for (int r = 0; r < 8; ++r) {
        int gr = row0 + ty * 8 + r;
        if (gr < M) {
            float4 o0, o1;
            o0.x = fmaxf(acc[r][0] + bv0.x, 0.f);
            o0.y = fmaxf(acc[r][1] + bv0.y, 0.f);
            o0.z = fmaxf(acc[r][2] + bv0.z, 0.f);
            o0.w = fmaxf(acc[r][3] + bv0.w, 0.f);
            o1.x = fmaxf(acc[r][4] + bv1.x, 0.f);
            o1.y = fmaxf(acc[r][5] + bv1.y, 0.f);
            o1.z = fmaxf(acc[r][6] + bv1.z, 0.f);
            o1.w = fmaxf(acc[r][7] + bv1.w, 0.f);
            out4[gr * 32 + tx] = o0;
            out4[gr * 32 + 16 + tx] = o1;
        }
    }
}

// Ordered pull aggregation (round-6 measured variant, 107us, DO NOT TOUCH):
// one wave = TWO nodes; lane holds a float4 feature quad (32 lanes x 16B =
// full 512B row -> one VMEM instr per edge-row). Per-feature fp32 add order
// strictly ascending-edge per node == np.add.at.
__global__ __launch_bounds__(256) void aggregate_kernel(const float* __restrict__ h,
                                                        const int* __restrict__ offs,
                                                        const int* __restrict__ csr_src,
                                                        float* __restrict__ agg, int n) {
    int w = (blockIdx.x * 256 + threadIdx.x) >> 6;   // wave id = node pair
    int lane = threadIdx.x & 63;
    int half = lane >> 5;
    int l32 = lane & 31;
    int node = w * 2 + half;
    bool nvalid = node < n;
    int beg = 0, deg = 0;
    if (nvalid) {
        beg = offs[node];
        deg = offs[node + 1] - beg;
    }
    int mdeg = max(deg, __shfl_xor(deg, 32));  // pair's max degree
    const float4* h4 = (const float4*)h;
    float ax = 0.f, ay = 0.f, az = 0.f, aw = 0.f;
    for (int base = 0; base < mdeg; base += 32) {
        int idx = base + l32;
        int sv = (nvalid && idx < deg) ? csr_src[beg + idx] : 0;
        int nk = mdeg - base; if (nk > 32) nk = 32;
#pragma unroll 4
        for (int j = 0; j < nk; ++j) {
            int s = __shfl(sv, (half << 5) | j);   // own half's j-th source
            if (base + j < deg) {                  // uniform per half
                float4 r = h4[s * 32 + l32];
                ax += r.x; ay += r.y; az += r.z; aw += r.w;
            }
        }
    }
    if (nvalid) {
        float4 o = make_float4(ax, ay, az, aw);
        ((float4*)agg)[(size_t)node * 32 + l32] = o;
    }
}

// One wave per post. hid[j]: fp32 sequential-k fmaf (matches sgemm).
// Final 64-dot in f64 (unamplified; truth-centered).
__global__ __launch_bounds__(256) void head_kernel(const float* __restrict__ h,
                                                   const int* __restrict__ mask,
                                                   const float* __restrict__ Wo1,
                                                   const float* __restrict__ bo1,
                                                   const float* __restrict__ Wo2,
                                                   const float* __restrict__ bo2,
                                                   float* __restrict__ out, int P) {
    __shared__ float hids[4][64];
    int wid = threadIdx.x >> 6;
    int lane = threadIdx.x & 63;
    int p = blockIdx.x * 4 + wid;
    if (p >= P) return;
    int node = mask[p];
    const float* row = h + (size_t)node * 128;
    float acc = 0.f;
#pragma unroll 4
    for (int k = 0; k < 128; ++k)
        acc = fmaf(row[k], Wo1[k * 64 + lane], acc);
    hids[wid][lane] = fmaxf(acc + bo1[lane], 0.f);
    if (lane == 0) {
        double lg = 0.0;
        for (int j = 0; j < 64; ++j)
            lg = fma((double)hids[wid][j], (double)Wo2[j], lg);
        lg += (double)bo2[0];
        out[p] = (float)(1.0 / (1.0 + exp(-lg)));
    }
}

extern "C" void kernel_launch(void* const* d_in, const int* in_sizes, int n_in,
                              void* d_out, int out_size, void* d_ws, size_t ws_size,
                              hipStream_t stream) {
    const float* NF   = (const float*)d_in[0];
    const int*   EI   = (const int*)d_in[1];
    const int*   MASK = (const int*)d_in[2];
    const float* Wenc = (const float*)d_in[3];
    const float* benc = (const float*)d_in[4];
    const float* W1   = (const float*)d_in[5];
    const float* b1   = (const float*)d_in[6];
    const float* W2   = (const float*)d_in[7];
    const float* b2   = (const float*)d_in[8];
    const float* Wo1  = (const float*)d_in[9];
    const float* bo1  = (const float*)d_in[10];
    const float* Wo2  = (const float*)d_in[11];
    const float* bo2  = (const float*)d_in[12];
    float* out = (float*)d_out;

    const int N = in_sizes[0] / 128;
    const int E = in_sizes[1] / 2;
    const int P = in_sizes[2];

    char* ws = (char*)d_ws;
    size_t off = 0;
    auto alloc = [&](size_t bytes) {
        char* pp = ws + off;
        off += (bytes + 255) & ~(size_t)255;
        return pp;
    };
    float* h       = (float*)alloc((size_t)N * 128 * 4);
    float* agg     = (float*)alloc((size_t)N * 128 * 4);
    int*   offs    = (int*)alloc((size_t)(N + 1) * 4);
    int*   csr_src = (int*)alloc((size_t)E * 4);
    const int NBLK = (E + RB_SIZE - 1) / RB_SIZE;
    const int NDIG = (N + 255) >> 8;
    int*   bh      = (int*)alloc((size_t)NDIG * NBLK * 4);
    int*   dtot    = (int*)alloc(256 * 4);
    // Alias (used strictly before gemm1 writes h):
    u64* rec_a = (u64*)h;      // pass-A records: 12.8 MB <= 25.6 MB

    const int* src = EI;
    const int* dst = EI + E;

    // --- fused cooperative sort: hist -> scans -> scatter -> bucket ---
    {
        const int* a_dst = dst; const int* a_src = src;
        u64* a_rec = rec_a; int* a_bh = bh; int* a_dtot = dtot;
        int* a_csr = csr_src; int* a_offs = offs;
        int a_E = E, a_N = N, a_NBLK = NBLK, a_NDIG = NDIG;
        void* kargs[] = { (void*)&a_dst, (void*)&a_src, (void*)&a_rec,
                          (void*)&a_bh, (void*)&a_dtot, (void*)&a_csr,
                          (void*)&a_offs, (void*)&a_E, (void*)&a_N,
                          (void*)&a_NBLK, (void*)&a_NDIG };
        int gridBlocks = (NBLK > NDIG) ? NBLK : NDIG;
        hipLaunchCooperativeKernel((void*)sort_coop, dim3(gridBlocks), dim3(256),
                                   kargs, 0, stream);
    }

    int gblocks = (N + 127) / 128;
    int ablocks = ((N + 1) / 2 + 3) / 4;   // one wave per node pair, 4 waves/block
    gemm128<false><<<gblocks, 256, 0, stream>>>(NF, nullptr, Wenc, benc, h, N);
    aggregate_kernel<<<ablocks, 256, 0, stream>>>(h, offs, csr_src, agg, N);
    gemm128<true><<<gblocks, 256, 0, stream>>>(h, agg, W1, b1, h, N);
    aggregate_kernel<<<ablocks, 256, 0, stream>>>(h, offs, csr_src, agg, N);
    gemm128<true><<<gblocks, 256, 0, stream>>>(h, agg, W2, b2, h, N);
    head_kernel<<<(P + 3) / 4, 256, 0, stream>>>(h, MASK, Wo1, bo1, Wo2, bo2, out, P);
}

// Round 12
// 396.559 us; speedup vs baseline: 1.5084x; 1.5084x over previous
//
#include <hip/hip_runtime.h>
#include <math.h>

// ---------------------------------------------------------------------------
// GCN forward, numerically matched to the numpy float32 reference:
//  - GEMMs: per-element sequential-k fp32 FMA chain (== BLAS sgemm microkernel)
//  - segment_sum: per-feature fp32 adds in ascending-edge order (== np.add.at)
//  - head final dot: f64 (no downstream amplification)
// NUMERICS ARE LOCKED (absmax 1e-13 since round 3): only scheduling/memory
// layout may change between rounds, never the fp32 op order.
//
// ROUND 12 = exact revert to round-10 (394.6us measured best).
// Round-11 lesson: fusing the sort into one cooperative kernel ran at 17%
// occupancy (56KB LDS, 391 blocks pinned) -> 248us vs ~60us as 6 separate
// full-occupancy dispatches. Don't trade device-wide occupancy for launches.
// CSR build: MSD-then-bucket stable sort (pass A by dst>>8, then per-group
// LDS counting sort by low byte; emits csr_src + offs).
// Aggregation = round-6 measured variant (107us, 344MB fetch ~= compulsory
// floor @ ~3.5TB/s L2-fill). DO NOT TOUCH (round-7 lesson).
// GEMM v3: 128x128 block, 8x8 per-thread, As XOR-swizzled (round-10; at floor).
// ---------------------------------------------------------------------------

typedef unsigned long long u64;

#define RB_SIZE    4096
#define RB_ROUNDS  16     // RB_SIZE / 256
#define BUCKET_CAP 9216   // mean 8192, sigma ~90 -> +11 sigma

// --- hierarchical exclusive scan: in[n] -> out[n] ---------------------------
__global__ __launch_bounds__(1024) void scan_part(const int* __restrict__ in,
                                                  int* __restrict__ bsum, int n) {
    __shared__ int red[1024];
    int i = blockIdx.x * 1024 + threadIdx.x;
    red[threadIdx.x] = (i < n) ? in[i] : 0;
    __syncthreads();
    for (int d = 512; d; d >>= 1) {
        if (threadIdx.x < d) red[threadIdx.x] += red[threadIdx.x + d];
        __syncthreads();
    }
    if (threadIdx.x == 0) bsum[blockIdx.x] = red[0];
}

// one block, parallel Hillis-Steele over nb<=256 block sums
__global__ __launch_bounds__(256) void scan_tops_par(const int* __restrict__ bsum,
                                                     int* __restrict__ bbase, int nb) {
    __shared__ int buf[256];
    int tid = threadIdx.x;
    int v = (tid < nb) ? bsum[tid] : 0;
    buf[tid] = v;
    __syncthreads();
    for (int s = 1; s < 256; s <<= 1) {
        int u = (tid >= s) ? buf[tid - s] : 0;
        __syncthreads();
        buf[tid] += u;
        __syncthreads();
    }
    if (tid < nb) bbase[tid] = buf[tid] - v;   // exclusive
}

__global__ __launch_bounds__(1024) void scan_final(const int* __restrict__ in,
                                                   const int* __restrict__ bbase,
                                                   int* __restrict__ out, int n) {
    __shared__ int buf[1024];
    int tid = threadIdx.x;
    int i = blockIdx.x * 1024 + tid;
    int c = (i < n) ? in[i] : 0;
    buf[tid] = c;
    __syncthreads();
    for (int d = 1; d < 1024; d <<= 1) {
        int v = (tid >= d) ? buf[tid - d] : 0;
        __syncthreads();
        buf[tid] += v;
        __syncthreads();
    }
    if (i < n) out[i] = bbase[blockIdx.x] + buf[tid] - c;
}

// --- pass A: histogram + stable scatter on HIGH byte -----------------------
__global__ __launch_bounds__(256) void radix_hist_hi(const int* __restrict__ dstArr,
                                                     int* __restrict__ blockhist,
                                                     int E, int NBLK) {
    __shared__ int cnt[256];
    cnt[threadIdx.x] = 0;
    __syncthreads();
    int base = blockIdx.x * RB_SIZE;
    for (int t = threadIdx.x; t < RB_SIZE; t += 256) {
        int i = base + t;
        if (i < E) atomicAdd(&cnt[dstArr[i] >> 8], 1);
    }
    __syncthreads();
    // digit-major layout [d*NBLK + b]: flat exclusive scan == stable base
    blockhist[threadIdx.x * NBLK + blockIdx.x] = cnt[threadIdx.x];
}

// Stable scatter by high byte. Block processes RB_SIZE records in 16 ordered
// rounds of 256. Rank among same-digit lanes via 8 ballots (lane order ==
// edge order -> stable); waves stacked via per-(digit,wave) LDS counts;
// rounds stacked via cursor. Deterministic, no atomics.
__global__ __launch_bounds__(256) void radix_scatter_hi(const int* __restrict__ dstArr,
                                                        const int* __restrict__ srcArr,
                                                        u64* __restrict__ recOut,
                                                        const int* __restrict__ blockbase,
                                                        int E, int NBLK) {
    __shared__ int cursor[256];
    __shared__ int gbase[256];
    __shared__ int cnt[256 * 4];     // [d*4 + wave]
    __shared__ int wbase[256 * 4];
    int tid = threadIdx.x;
    int wid = tid >> 6, lane = tid & 63;
    cursor[tid] = 0;
    gbase[tid] = blockbase[tid * NBLK + blockIdx.x];
    int base = blockIdx.x * RB_SIZE;
    __syncthreads();
    for (int r = 0; r < RB_ROUNDS; ++r) {
        int i = base + r * 256 + tid;
        bool valid = (i < E);
        int d = 0;
        u64 rec = 0;
        if (valid) {
            int dv = dstArr[i];
            rec = ((u64)(unsigned)srcArr[i] << 32) | (unsigned)dv;
            d = dv >> 8;
        }
        ((int4*)cnt)[tid] = make_int4(0, 0, 0, 0);   // zero all 1024 counts
        u64 mask = ~0ull;
#pragma unroll
        for (int b = 0; b < 8; ++b) {
            int bit = (d >> b) & 1;
            u64 bal = __ballot(bit);
            mask &= bit ? bal : ~bal;
        }
        mask &= __ballot(valid ? 1 : 0);
        int rank = __popcll(mask & (((u64)1 << lane) - 1));
        int wtot = __popcll(mask);
        __syncthreads();                 // cnt zeroed everywhere
        if (valid && rank == 0) cnt[d * 4 + wid] = wtot;  // one writer per (d,w)
        __syncthreads();
        {
            int run = cursor[tid];
#pragma unroll
            for (int w = 0; w < 4; ++w) {
                wbase[tid * 4 + w] = run;
                run += cnt[tid * 4 + w];
            }
            cursor[tid] = run;
        }
        __syncthreads();
        if (valid) recOut[gbase[d] + wbase[d * 4 + wid] + rank] = rec;
        __syncthreads();                 // protect wbase/cnt for next round
    }
}

// --- bucket kernel: per high-digit group, stable LDS counting sort by low
// byte; writes csr_src (sequential range) and offs for the group's 256 dst
// values. Group records arrive e-stable from pass A; placement preserves
// order within each low-byte bin -> final (dst, e) order == np.add.at.
__global__ __launch_bounds__(256) void bucket_kernel(const u64* __restrict__ rec,
                                                     const int* __restrict__ blockbase,
                                                     int* __restrict__ csr_src,
                                                     int* __restrict__ offs,
                                                     int E, int N, int NBLK, int NDIG) {
    __shared__ int srcs[BUCKET_CAP];
    __shared__ unsigned char lob[BUCKET_CAP];
    __shared__ int binb[256];
    __shared__ int cursor[256];
    __shared__ int cnt4[256 * 4];
    __shared__ int wbase4[256 * 4];
    int g = blockIdx.x;
    int tid = threadIdx.x;
    int wid = tid >> 6, lane = tid & 63;
    int gbeg = blockbase[g * NBLK];
    int gend = (g + 1 < NDIG) ? blockbase[(g + 1) * NBLK] : E;
    int cnt = gend - gbeg;
    if (cnt > BUCKET_CAP) cnt = BUCKET_CAP;   // statistically impossible
    binb[tid] = 0;
    __syncthreads();
    for (int i = tid; i < cnt; i += 256) {
        u64 r = rec[gbeg + i];
        srcs[i] = (int)(r >> 32);
        int lo = (int)(r & 255);
        lob[i] = (unsigned char)lo;
        atomicAdd(&binb[lo], 1);
    }
    __syncthreads();
    // exclusive scan of 256 bin counts (use cursor as scan buffer)
    int c = binb[tid];
    cursor[tid] = c;
    __syncthreads();
    for (int s = 1; s < 256; s <<= 1) {
        int v = (tid >= s) ? cursor[tid - s] : 0;
        __syncthreads();
        cursor[tid] += v;
        __syncthreads();
    }
    int excl = cursor[tid] - c;
    __syncthreads();
    binb[tid] = excl;
    cursor[tid] = excl;
    // offs for this group's dst values (empty bins handled naturally)
    int v = g * 256 + tid;
    if (v < N) offs[v] = gbeg + excl;
    if (g == NDIG - 1 && tid == 0) offs[N] = E;
    __syncthreads();
    // stable placement, rounds of 256 (ballot-rank + wave stacking)
    int nrounds = (cnt + 255) >> 8;
    for (int r = 0; r < nrounds; ++r) {
        int i = r * 256 + tid;
        bool valid = (i < cnt);
        int d = valid ? (int)lob[i] : 0;
        ((int4*)cnt4)[tid] = make_int4(0, 0, 0, 0);
        u64 mask = ~0ull;
#pragma unroll
        for (int b = 0; b < 8; ++b) {
            int bit = (d >> b) & 1;
            u64 bal = __ballot(bit);
            mask &= bit ? bal : ~bal;
        }
        mask &= __ballot(valid ? 1 : 0);
        int rank = __popcll(mask & (((u64)1 << lane) - 1));
        int wtot = __popcll(mask);
        __syncthreads();
        if (valid && rank == 0) cnt4[d * 4 + wid] = wtot;
        __syncthreads();
        {
            int run = cursor[tid];
#pragma unroll
            for (int w = 0; w < 4; ++w) {
                wbase4[tid * 4 + w] = run;
                run += cnt4[tid * 4 + w];
            }
            cursor[tid] = run;
        }
        __syncthreads();
        if (valid) csr_src[gbeg + wbase4[d * 4 + wid] + rank] = srcs[i];
        __syncthreads();
    }
}

// out[M,128] = relu((A (+A2)) @ W[128,128] + bias), fp32 sequential-k FMA
// chain per element (== sgemm). v3: 128x128 per block, 256 threads, 8x8 per
// thread; 16 FMA per ds_read_b128. As XOR-swizzled: f4-slot kf stored at
// kf ^ ((row>>3)&7). K order kh->k4->kk strictly ascending == same chain.
// In-place out==A safe: block reads only its own rows, writes after all reads.
template <bool FUSE>
__global__ __launch_bounds__(256) void gemm128(const float* __restrict__ A,
                                               const float* __restrict__ A2,
                                               const float* __restrict__ W,
                                               const float* __restrict__ bias,
                                               float* __restrict__ out, int M) {
    __shared__ float As[128 * 64];   // one K-half of A rows, swizzled: 32 KB
    __shared__ float Ws[64 * 128];   // one K-half of W: 32 KB
    int tid = threadIdx.x;
    int tx = tid & 15;               // 16 col groups (cols tx*4.. and 64+tx*4..)
    int ty = tid >> 4;               // 16 row groups (rows ty*8..ty*8+7)
    int row0 = blockIdx.x * 128;

    float acc[8][8];
#pragma unroll
    for (int r = 0; r < 8; ++r)
#pragma unroll
        for (int c = 0; c < 8; ++c) acc[r][c] = 0.f;

    const float4* A4 = (const float4*)A;
    const float4* A24 = (const float4*)A2;
    const float4* W4 = (const float4*)W;
    float4* As4 = (float4*)As;
    float4* Ws4 = (float4*)Ws;
    int swz = ty & 7;                // == (row>>3)&7 for this thread's rows

    for (int kh = 0; kh < 2; ++kh) {
        __syncthreads();             // protect LDS before overwrite
        // stage A rows (swizzled) + W half (linear)
#pragma unroll
        for (int j = 0; j < 8; ++j) {
            int idx = tid + 256 * j;             // 0..2047
            int r = idx >> 4, kf = idx & 15;
            int gr = row0 + r;
            float4 v = make_float4(0.f, 0.f, 0.f, 0.f);
            if (gr < M) {
                v = A4[gr * 32 + kh * 16 + kf];
                if (FUSE) {
                    float4 u = A24[gr * 32 + kh * 16 + kf];
                    v.x += u.x; v.y += u.y; v.z += u.z; v.w += u.w;  // agg+h
                }
            }
            As4[r * 16 + (kf ^ ((r >> 3) & 7))] = v;
            int k = idx >> 5, cf = idx & 31;
            Ws4[k * 32 + cf] = W4[(kh * 64 + k) * 32 + cf];
        }
        __syncthreads();

        // strictly ascending k: kh -> k4 -> kk; one dependent chain per acc
#pragma unroll 2
        for (int k4 = 0; k4 < 16; ++k4) {
            float4 a[8];
#pragma unroll
            for (int r = 0; r < 8; ++r)
                a[r] = As4[(ty * 8 + r) * 16 + (k4 ^ swz)];
#pragma unroll
            for (int kk = 0; kk < 4; ++kk) {
                float4 b0 = Ws4[(k4 * 4 + kk) * 32 + tx];
                float4 b1 = Ws4[(k4 * 4 + kk) * 32 + 16 + tx];
#pragma unroll
                for (int r = 0; r < 8; ++r) {
                    float av = (kk == 0) ? a[r].x : (kk == 1) ? a[r].y
                             : (kk == 2) ? a[r].z : a[r].w;
                    acc[r][0] = fmaf(av, b0.x, acc[r][0]);
                    acc[r][1] = fmaf(av, b0.y, acc[r][1]);
                    acc[r][2] = fmaf(av, b0.z, acc[r][2]);
                    acc[r][3] = fmaf(av, b0.w, acc[r][3]);
                    acc[r][4] = fmaf(av, b1.x, acc[r][4]);
                    acc[r][5] = fmaf(av, b1.y, acc[r][5]);
                    acc[r][6] = fmaf(av, b1.z, acc[r][6]);
                    acc[r][7] = fmaf(av, b1.w, acc[r][7]);
                }
            }
        }
    }

    float4 bv0 = ((const float4*)bias)[tx];
    float4 bv1 = ((const float4*)bias)[16 + tx];
    float4* out4 = (float4*)out;
#pragma unroll
    for (int r = 0; r < 8; ++r) {
        int gr = row0 + ty * 8 + r;
        if (gr < M) {
            float4 o0, o1;
            o0.x = fmaxf(acc[r][0] + bv0.x, 0.f);
            o0.y = fmaxf(acc[r][1] + bv0.y, 0.f);
            o0.z = fmaxf(acc[r][2] + bv0.z, 0.f);
            o0.w = fmaxf(acc[r][3] + bv0.w, 0.f);
            o1.x = fmaxf(acc[r][4] + bv1.x, 0.f);
            o1.y = fmaxf(acc[r][5] + bv1.y, 0.f);
            o1.z = fmaxf(acc[r][6] + bv1.z, 0.f);
            o1.w = fmaxf(acc[r][7] + bv1.w, 0.f);
            out4[gr * 32 + tx] = o0;
            out4[gr * 32 + 16 + tx] = o1;
        }
    }
}

// Ordered pull aggregation (round-6 measured variant, 107us, DO NOT TOUCH):
// one wave = TWO nodes. Lanes 0-31 node A, 32-63 node B; each lane holds a
// float4 feature quad (32 lanes x 16B = full 512B row -> one VMEM instr per
// edge-row). Per-feature fp32 add order strictly ascending-edge per node.
__global__ __launch_bounds__(256) void aggregate_kernel(const float* __restrict__ h,
                                                        const int* __restrict__ offs,
                                                        const int* __restrict__ csr_src,
                                                        float* __restrict__ agg, int n) {
    int w = (blockIdx.x * 256 + threadIdx.x) >> 6;   // wave id = node pair
    int lane = threadIdx.x & 63;
    int half = lane >> 5;
    int l32 = lane & 31;
    int node = w * 2 + half;
    bool nvalid = node < n;
    int beg = 0, deg = 0;
    if (nvalid) {
        beg = offs[node];
        deg = offs[node + 1] - beg;
    }
    int mdeg = max(deg, __shfl_xor(deg, 32));  // pair's max degree
    const float4* h4 = (const float4*)h;
    float ax = 0.f, ay = 0.f, az = 0.f, aw = 0.f;
    for (int base = 0; base < mdeg; base += 32) {
        int idx = base + l32;
        int sv = (nvalid && idx < deg) ? csr_src[beg + idx] : 0;
        int nk = mdeg - base; if (nk > 32) nk = 32;
#pragma unroll 4
        for (int j = 0; j < nk; ++j) {
            int s = __shfl(sv, (half << 5) | j);   // own half's j-th source
            if (base + j < deg) {                  // uniform per half
                float4 r = h4[s * 32 + l32];
                ax += r.x; ay += r.y; az += r.z; aw += r.w;
            }
        }
    }
    if (nvalid) {
        float4 o = make_float4(ax, ay, az, aw);
        ((float4*)agg)[(size_t)node * 32 + l32] = o;
    }
}

// One wave per post. hid[j]: fp32 sequential-k fmaf (matches sgemm).
// Final 64-dot in f64 (unamplified; truth-centered).
__global__ __launch_bounds__(256) void head_kernel(const float* __restrict__ h,
                                                   const int* __restrict__ mask,
                                                   const float* __restrict__ Wo1,
                                                   const float* __restrict__ bo1,
                                                   const float* __restrict__ Wo2,
                                                   const float* __restrict__ bo2,
                                                   float* __restrict__ out, int P) {
    __shared__ float hids[4][64];
    int wid = threadIdx.x >> 6;
    int lane = threadIdx.x & 63;
    int p = blockIdx.x * 4 + wid;
    if (p >= P) return;
    int node = mask[p];
    const float* row = h + (size_t)node * 128;
    float acc = 0.f;
#pragma unroll 4
    for (int k = 0; k < 128; ++k)
        acc = fmaf(row[k], Wo1[k * 64 + lane], acc);
    hids[wid][lane] = fmaxf(acc + bo1[lane], 0.f);
    if (lane == 0) {
        double lg = 0.0;
        for (int j = 0; j < 64; ++j)
            lg = fma((double)hids[wid][j], (double)Wo2[j], lg);
        lg += (double)bo2[0];
        out[p] = (float)(1.0 / (1.0 + exp(-lg)));
    }
}

extern "C" void kernel_launch(void* const* d_in, const int* in_sizes, int n_in,
                              void* d_out, int out_size, void* d_ws, size_t ws_size,
                              hipStream_t stream) {
    const float* NF   = (const float*)d_in[0];
    const int*   EI   = (const int*)d_in[1];
    const int*   MASK = (const int*)d_in[2];
    const float* Wenc = (const float*)d_in[3];
    const float* benc = (const float*)d_in[4];
    const float* W1   = (const float*)d_in[5];
    const float* b1   = (const float*)d_in[6];
    const float* W2   = (const float*)d_in[7];
    const float* b2   = (const float*)d_in[8];
    const float* Wo1  = (const float*)d_in[9];
    const float* bo1  = (const float*)d_in[10];
    const float* Wo2  = (const float*)d_in[11];
    const float* bo2  = (const float*)d_in[12];
    float* out = (float*)d_out;

    const int N = in_sizes[0] / 128;
    const int E = in_sizes[1] / 2;
    const int P = in_sizes[2];

    char* ws = (char*)d_ws;
    size_t off = 0;
    auto alloc = [&](size_t bytes) {
        char* pp = ws + off;
        off += (bytes + 255) & ~(size_t)255;
        return pp;
    };
    float* h       = (float*)alloc((size_t)N * 128 * 4);
    float* agg     = (float*)alloc((size_t)N * 128 * 4);
    int*   offs    = (int*)alloc((size_t)(N + 1) * 4);
    int*   csr_src = (int*)alloc((size_t)E * 4);
    const int NBLK = (E + RB_SIZE - 1) / RB_SIZE;
    int*   bh      = (int*)alloc((size_t)256 * NBLK * 4);
    int*   bb      = (int*)alloc((size_t)256 * NBLK * 4);
    int*   bsum    = (int*)alloc(256 * 4);
    int*   bbase   = (int*)alloc(256 * 4);
    // Alias (used strictly before gemm1 writes h):
    u64* rec_a = (u64*)h;      // pass-A records: 12.8 MB <= 25.6 MB

    const int* src = EI;
    const int* dst = EI + E;

    const int NDIG = (N + 255) >> 8;       // 196 high-byte groups
    const int L = NDIG * NBLK;             // flat blockhist length
    const int nscanL = (L + 1023) / 1024;  // 75 <= 256

    // --- pass A: stable scatter by dst>>8 ---
    radix_hist_hi<<<NBLK, 256, 0, stream>>>(dst, bh, E, NBLK);
    scan_part<<<nscanL, 1024, 0, stream>>>(bh, bsum, L);
    scan_tops_par<<<1, 256, 0, stream>>>(bsum, bbase, nscanL);
    scan_final<<<nscanL, 1024, 0, stream>>>(bh, bbase, bb, L);
    radix_scatter_hi<<<NBLK, 256, 0, stream>>>(dst, src, rec_a, bb, E, NBLK);

    // --- bucket: LDS stable counting sort by low byte -> csr_src + offs ---
    bucket_kernel<<<NDIG, 256, 0, stream>>>(rec_a, bb, csr_src, offs, E, N, NBLK, NDIG);

    int gblocks = (N + 127) / 128;
    int ablocks = ((N + 1) / 2 + 3) / 4;   // one wave per node pair, 4 waves/block
    gemm128<false><<<gblocks, 256, 0, stream>>>(NF, nullptr, Wenc, benc, h, N);
    aggregate_kernel<<<ablocks, 256, 0, stream>>>(h, offs, csr_src, agg, N);
    gemm128<true><<<gblocks, 256, 0, stream>>>(h, agg, W1, b1, h, N);
    aggregate_kernel<<<ablocks, 256, 0, stream>>>(h, offs, csr_src, agg, N);
    gemm128<true><<<gblocks, 256, 0, stream>>>(h, agg, W2, b2, h, N);
    head_kernel<<<(P + 3) / 4, 256, 0, stream>>>(h, MASK, Wo1, bo1, Wo2, bo2, out, P);
}